// Round 1
// baseline (93.789 us; speedup 1.0000x reference)
//
#include <hip/hip_runtime.h>
#include <math.h>

// TopologyHead: persistence image (B,64,64) + persistence landscapes (B,5,256)
// B=64, N=4096. Output = [image flat 262144][landscapes flat 81920], fp32.
//
// 3 dispatches:
//  k_minmax : per-batch min birth / max death -> wsf[0..127]
//  k_main   : blocks [0,256)   = image bf16-MFMA K-split GEMM (KC=4)
//             blocks [256,768) = landscape top-5 partials (1 wave per
//                                128-pt chunk, 4 r per lane, med3 insert,
//                                wave-uniform global point loads)
//  k_finish : per-batch: sum KC image partials + max + normalize;
//             merge 32 partial top-5 lists per r.

#define B_   64
#define N_   4096
#define HW_  64
#define RES_ 256
#define EPSF 1e-8f
#define KC_  4          // image K-split (1024 points per img block)
#define CPB  1024       // points per image block
#define KP   64         // points per staged LDS chunk (img)
#define PCW  32         // landscape point-chunks per batch (waves)
#define LCH  (N_ / PCW) // 128 points per landscape wave

typedef short short8v  __attribute__((ext_vector_type(8)));
typedef float float4v  __attribute__((ext_vector_type(4)));

__device__ __forceinline__ unsigned short f2bf(float f) {
    unsigned int u = __float_as_uint(f);
    u += 0x7fffu + ((u >> 16) & 1u);          // round-nearest-even
    return (unsigned short)(u >> 16);
}

// sorted-desc 5-list insert, 5 ops via med3; x<0 is a no-op (list >= 0)
#define INS5(v0, v1, v2, v3, v4, x)                       \
    {                                                     \
        float _p0 = v0, _p1 = v1, _p2 = v2, _p3 = v3;     \
        v0 = fmaxf(_p0, x);                               \
        v1 = __builtin_amdgcn_fmed3f(_p0, _p1, x);        \
        v2 = __builtin_amdgcn_fmed3f(_p1, _p2, x);        \
        v3 = __builtin_amdgcn_fmed3f(_p2, _p3, x);        \
        v4 = __builtin_amdgcn_fmed3f(_p3, v4, x);         \
    }

// ---------------- kernel 1: per-batch min birth / max death ----------------
__global__ __launch_bounds__(256) void k_minmax(const float* __restrict__ pairs,
                                                float* __restrict__ wsf) {
    int b = blockIdx.x, tid = threadIdx.x;
    const float2* pr = (const float2*)pairs + (size_t)b * N_;
    float mn = 1e30f, mx = -1e30f;
    #pragma unroll
    for (int i = 0; i < N_ / 256; ++i) {
        float2 v = pr[tid + i * 256];
        mn = fminf(mn, v.x);
        mx = fmaxf(mx, v.y);
    }
    #pragma unroll
    for (int off = 32; off > 0; off >>= 1) {
        mn = fminf(mn, __shfl_xor(mn, off, 64));
        mx = fmaxf(mx, __shfl_xor(mx, off, 64));
    }
    __shared__ float smn[4], smx[4];
    if ((tid & 63) == 0) { smn[tid >> 6] = mn; smx[tid >> 6] = mx; }
    __syncthreads();
    if (tid == 0) {
        mn = fminf(fminf(smn[0], smn[1]), fminf(smn[2], smn[3]));
        mx = fmaxf(fmaxf(smx[0], smx[1]), fmaxf(smx[2], smx[3]));
        wsf[b]      = mn;
        wsf[64 + b] = mx;
    }
}

// ---------------- kernel 2: fused image-MFMA + landscape partials ----------------
__global__ __launch_bounds__(256) void k_main(const float* __restrict__ pairs,
                                              const float* __restrict__ sigp,
                                              const float* __restrict__ wsf,
                                              float* __restrict__ part,
                                              float* __restrict__ lp) {
    __shared__ unsigned short gy_lds[64 * 72];
    __shared__ unsigned short gx_lds[64 * 72];
    __shared__ float2 pts_lds[CPB];

    int tid = threadIdx.x;
    int l = tid & 63, w = tid >> 6;

    if (blockIdx.x < 256) {
        // ================= image path: bf16 MFMA K-split GEMM =================
        int kc = blockIdx.x & 3, b = blockIdx.x >> 2;
        float sigma = sigp[0];
        float cc = 0.5f / (sigma * sigma);

        const float4* src = (const float4*)(pairs + 2 * ((size_t)b * N_ + kc * CPB));
        ((float4*)pts_lds)[tid]       = src[tid];
        ((float4*)pts_lds)[256 + tid] = src[256 + tid];

        int c  = tid & 63;          // coordinate this thread stages
        int pg = tid >> 6;          // point sub-group
        float xc = (float)c * (1.0f / 63.0f);

        float4v acc[4];
        #pragma unroll
        for (int c4 = 0; c4 < 4; ++c4) acc[c4] = (float4v){0.f, 0.f, 0.f, 0.f};

        int rowA = (w * 16 + (l & 15)) * 72 + (l >> 4) * 8;

        for (int ch = 0; ch < CPB / KP; ++ch) {
            __syncthreads();
            int p0 = ch * KP + pg * 16;
            alignas(16) unsigned short gyb[16], gxb[16];
            #pragma unroll
            for (int j = 0; j < 16; ++j) {
                float2 q = pts_lds[p0 + j];
                float pe = q.y - q.x;
                float dx = xc - q.x;
                float dy = xc - pe;
                gxb[j] = f2bf(__expf(-dx * dx * cc));
                gyb[j] = f2bf(pe * __expf(-dy * dy * cc));
            }
            *(uint4*)&gy_lds[c * 72 + pg * 16]     = *(uint4*)&gyb[0];
            *(uint4*)&gy_lds[c * 72 + pg * 16 + 8] = *(uint4*)&gyb[8];
            *(uint4*)&gx_lds[c * 72 + pg * 16]     = *(uint4*)&gxb[0];
            *(uint4*)&gx_lds[c * 72 + pg * 16 + 8] = *(uint4*)&gxb[8];
            __syncthreads();
            #pragma unroll
            for (int ks = 0; ks < 2; ++ks) {
                short8v af = *(const short8v*)&gy_lds[rowA + ks * 32];
                #pragma unroll
                for (int c4 = 0; c4 < 4; ++c4) {
                    short8v bf = *(const short8v*)
                        &gx_lds[(c4 * 16 + (l & 15)) * 72 + ks * 32 + (l >> 4) * 8];
                    acc[c4] = __builtin_amdgcn_mfma_f32_16x16x32_bf16(af, bf, acc[c4], 0, 0, 0);
                }
            }
        }

        float* dst = part + (size_t)(b * KC_ + kc) * (HW_ * HW_);
        #pragma unroll
        for (int c4 = 0; c4 < 4; ++c4)
            #pragma unroll
            for (int reg = 0; reg < 4; ++reg) {
                int h = w * 16 + (l >> 4) * 4 + reg;
                int wv = c4 * 16 + (l & 15);
                dst[h * HW_ + wv] = acc[c4][reg];
            }
    } else {
        // ================= landscape path: top-5 partials =================
        // one wave per 128-point chunk; lane owns r = l, l+64, l+128, l+192
        int idx = blockIdx.x - 256;            // 0..511
        int b = idx >> 3, pcb = idx & 7;
        int pc = pcb * 4 + w;                  // 0..31
        float minb = wsf[b], maxd = wsf[64 + b];
        float sc = (maxd - minb) * (1.0f / 255.0f);
        float t0 = minb + sc * (float)l;
        float t1 = t0 + sc * 64.0f;
        float t2 = t0 + sc * 128.0f;
        float t3 = t0 + sc * 192.0f;

        float a0 = 0.f, a1 = 0.f, a2 = 0.f, a3 = 0.f, a4 = 0.f;
        float b0 = 0.f, b1 = 0.f, b2 = 0.f, b3 = 0.f, b4 = 0.f;
        float c0 = 0.f, c1 = 0.f, c2 = 0.f, c3 = 0.f, c4 = 0.f;
        float d0 = 0.f, d1 = 0.f, d2 = 0.f, d3 = 0.f, d4 = 0.f;

        const float4* pw = (const float4*)(pairs + 2 * ((size_t)b * N_ + pc * LCH));
        #pragma unroll 4
        for (int p = 0; p < LCH / 2; ++p) {
            float4 q = pw[p];                  // wave-uniform, 2 points
            {
                float bb = q.x, dd = q.y;
                float x;
                x = fminf(t0 - bb, dd - t0); INS5(a0, a1, a2, a3, a4, x);
                x = fminf(t1 - bb, dd - t1); INS5(b0, b1, b2, b3, b4, x);
                x = fminf(t2 - bb, dd - t2); INS5(c0, c1, c2, c3, c4, x);
                x = fminf(t3 - bb, dd - t3); INS5(d0, d1, d2, d3, d4, x);
            }
            {
                float bb = q.z, dd = q.w;
                float x;
                x = fminf(t0 - bb, dd - t0); INS5(a0, a1, a2, a3, a4, x);
                x = fminf(t1 - bb, dd - t1); INS5(b0, b1, b2, b3, b4, x);
                x = fminf(t2 - bb, dd - t2); INS5(c0, c1, c2, c3, c4, x);
                x = fminf(t3 - bb, dd - t3); INS5(d0, d1, d2, d3, d4, x);
            }
        }

        // plane layout: lp[((b*PCW+pc)*5 + lvl)*RES + r] -- coalesced merge reads
        float* dst = lp + (size_t)(b * PCW + pc) * 5 * RES_;
        dst[0*RES_ + l]       = a0; dst[1*RES_ + l]       = a1;
        dst[2*RES_ + l]       = a2; dst[3*RES_ + l]       = a3;
        dst[4*RES_ + l]       = a4;
        dst[0*RES_ + l + 64]  = b0; dst[1*RES_ + l + 64]  = b1;
        dst[2*RES_ + l + 64]  = b2; dst[3*RES_ + l + 64]  = b3;
        dst[4*RES_ + l + 64]  = b4;
        dst[0*RES_ + l + 128] = c0; dst[1*RES_ + l + 128] = c1;
        dst[2*RES_ + l + 128] = c2; dst[3*RES_ + l + 128] = c3;
        dst[4*RES_ + l + 128] = c4;
        dst[0*RES_ + l + 192] = d0; dst[1*RES_ + l + 192] = d1;
        dst[2*RES_ + l + 192] = d2; dst[3*RES_ + l + 192] = d3;
        dst[4*RES_ + l + 192] = d4;
    }
}

// ---------------- kernel 3: image finish + landscape merge ----------------
__global__ __launch_bounds__(256) void k_finish(const float* __restrict__ part,
                                                const float* __restrict__ lp,
                                                float* __restrict__ out) {
    int b = blockIdx.x, tid = threadIdx.x;

    // ---- image: sum KC partials, block max, normalize ----
    const float4* p0 = (const float4*)(part + (size_t)b * KC_ * (HW_ * HW_));
    float4 s[4];
    float m = 0.0f;                                  // image values >= 0
    #pragma unroll
    for (int i = 0; i < 4; ++i) {
        int pix4 = tid + i * 256;
        float4 v = p0[pix4];
        #pragma unroll
        for (int kc = 1; kc < KC_; ++kc) {
            float4 u = p0[(size_t)kc * 1024 + pix4];
            v.x += u.x; v.y += u.y; v.z += u.z; v.w += u.w;
        }
        s[i] = v;
        m = fmaxf(m, fmaxf(fmaxf(v.x, v.y), fmaxf(v.z, v.w)));
    }
    #pragma unroll
    for (int off = 32; off > 0; off >>= 1) m = fmaxf(m, __shfl_xor(m, off, 64));
    __shared__ float sm[4];
    if ((tid & 63) == 0) sm[tid >> 6] = m;
    __syncthreads();
    m = fmaxf(fmaxf(sm[0], sm[1]), fmaxf(sm[2], sm[3]));
    float inv = 1.0f / (m + EPSF);
    float4* od = (float4*)(out + (size_t)b * (HW_ * HW_));
    #pragma unroll
    for (int i = 0; i < 4; ++i) {
        float4 v = s[i];
        v.x *= inv; v.y *= inv; v.z *= inv; v.w *= inv;
        od[tid + i * 256] = v;
    }

    // ---- landscapes: merge PCW partial top-5 lists for r = tid ----
    float v0 = 0.f, v1 = 0.f, v2 = 0.f, v3 = 0.f, v4 = 0.f;
    const float* lpb = lp + (size_t)b * PCW * 5 * RES_;
    for (int pc = 0; pc < PCW; ++pc) {
        #pragma unroll
        for (int lvl = 0; lvl < 5; ++lvl) {
            float x = lpb[(pc * 5 + lvl) * RES_ + tid];
            INS5(v0, v1, v2, v3, v4, x);
        }
    }
    float* o = out + (size_t)B_ * HW_ * HW_ + (size_t)b * (5 * RES_);
    o[tid]            = v0;
    o[RES_ + tid]     = v1;
    o[2 * RES_ + tid] = v2;
    o[3 * RES_ + tid] = v3;
    o[4 * RES_ + tid] = v4;
}

extern "C" void kernel_launch(void* const* d_in, const int* in_sizes, int n_in,
                              void* d_out, int out_size, void* d_ws, size_t ws_size,
                              hipStream_t stream) {
    const float* pairs = (const float*)d_in[0];
    const float* sig   = (const float*)d_in[1];
    float* out = (float*)d_out;
    float* wsf = (float*)d_ws;

    // ws layout (floats): [0..127] min/max | part (B*KC*4096 = 1M) | lp (B*32*5*256 = 2.62M)
    float* part = wsf + 128;
    float* lp   = part + (size_t)B_ * KC_ * HW_ * HW_;

    k_minmax<<<B_, 256, 0, stream>>>(pairs, wsf);
    k_main<<<768, 256, 0, stream>>>(pairs, sig, wsf, part, lp);
    k_finish<<<B_, 256, 0, stream>>>(part, lp, out);
}

// Round 4
// 93.418 us; speedup vs baseline: 1.0040x; 1.0040x over previous
//
#include <hip/hip_runtime.h>
#include <math.h>

// TopologyHead: persistence image (B,64,64) + persistence landscapes (B,5,256)
// B=64, N=4096. Output = [image flat 262144][landscapes flat 81920], fp32.
//
// 3 dispatches:
//  k_minmax : per-batch min birth / max death -> wsf[0..127]
//  k_main   : blocks [0,256)   = image bf16-MFMA K-split GEMM (KC=4)
//             blocks [256,768) = landscape top-5 partials
//  k_finish : per-batch: sum KC image partials + max + normalize;
//             merge 32 partial top-5 lists per r.
//
// R3: baseline structure (single-buffer, f2bf pack, alignas(16)) + ONLY the
//     verified exp2 transform: points staged as (b*s, pe*s, log2 pe),
//     s = sqrt(cc*log2e); gx = 2^(-dx^2), gy = 2^(fma(dy,-dy,l2pe)).

#define B_   64
#define N_   4096
#define HW_  64
#define RES_ 256
#define EPSF 1e-8f
#define KC_  4          // image K-split (1024 points per img block)
#define CPB  1024       // points per image block
#define KP   64         // points per staged LDS chunk (img)
#define PCW  32         // landscape point-chunks per batch (waves)
#define LCH  (N_ / PCW) // 128 points per landscape wave

typedef short short8v  __attribute__((ext_vector_type(8)));
typedef float float4v  __attribute__((ext_vector_type(4)));

__device__ __forceinline__ unsigned short f2bf(float f) {
    unsigned int u = __float_as_uint(f);
    u += 0x7fffu + ((u >> 16) & 1u);          // round-nearest-even
    return (unsigned short)(u >> 16);
}

// sorted-desc 5-list insert, 5 ops via med3; x<0 is a no-op (list >= 0)
#define INS5(v0, v1, v2, v3, v4, x)                       \
    {                                                     \
        float _p0 = v0, _p1 = v1, _p2 = v2, _p3 = v3;     \
        v0 = fmaxf(_p0, x);                               \
        v1 = __builtin_amdgcn_fmed3f(_p0, _p1, x);        \
        v2 = __builtin_amdgcn_fmed3f(_p1, _p2, x);        \
        v3 = __builtin_amdgcn_fmed3f(_p2, _p3, x);        \
        v4 = __builtin_amdgcn_fmed3f(_p3, v4, x);         \
    }

// ---------------- kernel 1: per-batch min birth / max death ----------------
__global__ __launch_bounds__(256) void k_minmax(const float* __restrict__ pairs,
                                                float* __restrict__ wsf) {
    int b = blockIdx.x, tid = threadIdx.x;
    const float2* pr = (const float2*)pairs + (size_t)b * N_;
    float mn = 1e30f, mx = -1e30f;
    #pragma unroll
    for (int i = 0; i < N_ / 256; ++i) {
        float2 v = pr[tid + i * 256];
        mn = fminf(mn, v.x);
        mx = fmaxf(mx, v.y);
    }
    #pragma unroll
    for (int off = 32; off > 0; off >>= 1) {
        mn = fminf(mn, __shfl_xor(mn, off, 64));
        mx = fmaxf(mx, __shfl_xor(mx, off, 64));
    }
    __shared__ float smn[4], smx[4];
    if ((tid & 63) == 0) { smn[tid >> 6] = mn; smx[tid >> 6] = mx; }
    __syncthreads();
    if (tid == 0) {
        mn = fminf(fminf(smn[0], smn[1]), fminf(smn[2], smn[3]));
        mx = fmaxf(fmaxf(smx[0], smx[1]), fmaxf(smx[2], smx[3]));
        wsf[b]      = mn;
        wsf[64 + b] = mx;
    }
}

// ---------------- kernel 2: fused image-MFMA + landscape partials ----------------
__global__ __launch_bounds__(256) void k_main(const float* __restrict__ pairs,
                                              const float* __restrict__ sigp,
                                              const float* __restrict__ wsf,
                                              float* __restrict__ part,
                                              float* __restrict__ lp) {
    __shared__ unsigned short gy_lds[64 * 72];
    __shared__ unsigned short gx_lds[64 * 72];
    __shared__ float4 pts_lds[CPB];    // (b*s, pe*s, log2(pe), 0) per point

    int tid = threadIdx.x;
    int l = tid & 63, w = tid >> 6;

    if (blockIdx.x < 256) {
        // ================= image path: bf16 MFMA K-split GEMM =================
        int kc = blockIdx.x & 3, b = blockIdx.x >> 2;
        float sigma = sigp[0];
        float cc = 0.5f / (sigma * sigma);
        float s = sqrtf(cc * 1.4426950408889634f);   // sqrt(cc * log2 e)

        const float4* src = (const float4*)(pairs + 2 * ((size_t)b * N_ + kc * CPB));
        float4 r0 = src[tid];
        float4 r1 = src[256 + tid];
        {
            float pe;
            pe = r0.y - r0.x;
            pts_lds[2 * tid]           = make_float4(r0.x * s, pe * s, __log2f(pe), 0.f);
            pe = r0.w - r0.z;
            pts_lds[2 * tid + 1]       = make_float4(r0.z * s, pe * s, __log2f(pe), 0.f);
            pe = r1.y - r1.x;
            pts_lds[512 + 2 * tid]     = make_float4(r1.x * s, pe * s, __log2f(pe), 0.f);
            pe = r1.w - r1.z;
            pts_lds[512 + 2 * tid + 1] = make_float4(r1.z * s, pe * s, __log2f(pe), 0.f);
        }

        int c  = tid & 63;          // coordinate this thread stages
        int pg = tid >> 6;          // point sub-group
        float xs = (float)c * (1.0f / 63.0f) * s;

        float4v acc[4];
        #pragma unroll
        for (int c4 = 0; c4 < 4; ++c4) acc[c4] = (float4v){0.f, 0.f, 0.f, 0.f};

        int rowA = (w * 16 + (l & 15)) * 72 + (l >> 4) * 8;

        for (int ch = 0; ch < CPB / KP; ++ch) {
            __syncthreads();
            int p0 = ch * KP + pg * 16;
            alignas(16) unsigned short gyb[16], gxb[16];
            #pragma unroll
            for (int j = 0; j < 16; ++j) {
                float4 q = pts_lds[p0 + j];
                float dx = xs - q.x;
                float dy = xs - q.y;
                gxb[j] = f2bf(__builtin_amdgcn_exp2f(-(dx * dx)));
                gyb[j] = f2bf(__builtin_amdgcn_exp2f(fmaf(dy, -dy, q.z)));
            }
            *(uint4*)&gy_lds[c * 72 + pg * 16]     = *(uint4*)&gyb[0];
            *(uint4*)&gy_lds[c * 72 + pg * 16 + 8] = *(uint4*)&gyb[8];
            *(uint4*)&gx_lds[c * 72 + pg * 16]     = *(uint4*)&gxb[0];
            *(uint4*)&gx_lds[c * 72 + pg * 16 + 8] = *(uint4*)&gxb[8];
            __syncthreads();
            #pragma unroll
            for (int ks = 0; ks < 2; ++ks) {
                short8v af = *(const short8v*)&gy_lds[rowA + ks * 32];
                #pragma unroll
                for (int c4 = 0; c4 < 4; ++c4) {
                    short8v bf = *(const short8v*)
                        &gx_lds[(c4 * 16 + (l & 15)) * 72 + ks * 32 + (l >> 4) * 8];
                    acc[c4] = __builtin_amdgcn_mfma_f32_16x16x32_bf16(af, bf, acc[c4], 0, 0, 0);
                }
            }
        }

        float* dst = part + (size_t)(b * KC_ + kc) * (HW_ * HW_);
        #pragma unroll
        for (int c4 = 0; c4 < 4; ++c4)
            #pragma unroll
            for (int reg = 0; reg < 4; ++reg) {
                int h = w * 16 + (l >> 4) * 4 + reg;
                int wv = c4 * 16 + (l & 15);
                dst[h * HW_ + wv] = acc[c4][reg];
            }
    } else {
        // ================= landscape path: top-5 partials =================
        // one wave per 128-point chunk; lane owns r = l, l+64, l+128, l+192
        int idx = blockIdx.x - 256;            // 0..511
        int b = idx >> 3, pcb = idx & 7;
        int pc = pcb * 4 + w;                  // 0..31
        float minb = wsf[b], maxd = wsf[64 + b];
        float sc = (maxd - minb) * (1.0f / 255.0f);
        float t0 = minb + sc * (float)l;
        float t1 = t0 + sc * 64.0f;
        float t2 = t0 + sc * 128.0f;
        float t3 = t0 + sc * 192.0f;

        float a0 = 0.f, a1 = 0.f, a2 = 0.f, a3 = 0.f, a4 = 0.f;
        float b0 = 0.f, b1 = 0.f, b2 = 0.f, b3 = 0.f, b4 = 0.f;
        float c0 = 0.f, c1 = 0.f, c2 = 0.f, c3 = 0.f, c4 = 0.f;
        float d0 = 0.f, d1 = 0.f, d2 = 0.f, d3 = 0.f, d4 = 0.f;

        const float4* pw = (const float4*)(pairs + 2 * ((size_t)b * N_ + pc * LCH));
        #pragma unroll 4
        for (int p = 0; p < LCH / 2; ++p) {
            float4 q = pw[p];                  // wave-uniform, 2 points
            {
                float bb = q.x, dd = q.y;
                float x;
                x = fminf(t0 - bb, dd - t0); INS5(a0, a1, a2, a3, a4, x);
                x = fminf(t1 - bb, dd - t1); INS5(b0, b1, b2, b3, b4, x);
                x = fminf(t2 - bb, dd - t2); INS5(c0, c1, c2, c3, c4, x);
                x = fminf(t3 - bb, dd - t3); INS5(d0, d1, d2, d3, d4, x);
            }
            {
                float bb = q.z, dd = q.w;
                float x;
                x = fminf(t0 - bb, dd - t0); INS5(a0, a1, a2, a3, a4, x);
                x = fminf(t1 - bb, dd - t1); INS5(b0, b1, b2, b3, b4, x);
                x = fminf(t2 - bb, dd - t2); INS5(c0, c1, c2, c3, c4, x);
                x = fminf(t3 - bb, dd - t3); INS5(d0, d1, d2, d3, d4, x);
            }
        }

        // plane layout: lp[((b*PCW+pc)*5 + lvl)*RES + r] -- coalesced merge reads
        float* dst = lp + (size_t)(b * PCW + pc) * 5 * RES_;
        dst[0*RES_ + l]       = a0; dst[1*RES_ + l]       = a1;
        dst[2*RES_ + l]       = a2; dst[3*RES_ + l]       = a3;
        dst[4*RES_ + l]       = a4;
        dst[0*RES_ + l + 64]  = b0; dst[1*RES_ + l + 64]  = b1;
        dst[2*RES_ + l + 64]  = b2; dst[3*RES_ + l + 64]  = b3;
        dst[4*RES_ + l + 64]  = b4;
        dst[0*RES_ + l + 128] = c0; dst[1*RES_ + l + 128] = c1;
        dst[2*RES_ + l + 128] = c2; dst[3*RES_ + l + 128] = c3;
        dst[4*RES_ + l + 128] = c4;
        dst[0*RES_ + l + 192] = d0; dst[1*RES_ + l + 192] = d1;
        dst[2*RES_ + l + 192] = d2; dst[3*RES_ + l + 192] = d3;
        dst[4*RES_ + l + 192] = d4;
    }
}

// ---------------- kernel 3: image finish + landscape merge ----------------
__global__ __launch_bounds__(256) void k_finish(const float* __restrict__ part,
                                                const float* __restrict__ lp,
                                                float* __restrict__ out) {
    int b = blockIdx.x, tid = threadIdx.x;

    // ---- image: sum KC partials, block max, normalize ----
    const float4* p0 = (const float4*)(part + (size_t)b * KC_ * (HW_ * HW_));
    float4 s[4];
    float m = 0.0f;                                  // image values >= 0
    #pragma unroll
    for (int i = 0; i < 4; ++i) {
        int pix4 = tid + i * 256;
        float4 v = p0[pix4];
        #pragma unroll
        for (int kc = 1; kc < KC_; ++kc) {
            float4 u = p0[(size_t)kc * 1024 + pix4];
            v.x += u.x; v.y += u.y; v.z += u.z; v.w += u.w;
        }
        s[i] = v;
        m = fmaxf(m, fmaxf(fmaxf(v.x, v.y), fmaxf(v.z, v.w)));
    }
    #pragma unroll
    for (int off = 32; off > 0; off >>= 1) m = fmaxf(m, __shfl_xor(m, off, 64));
    __shared__ float sm[4];
    if ((tid & 63) == 0) sm[tid >> 6] = m;
    __syncthreads();
    m = fmaxf(fmaxf(sm[0], sm[1]), fmaxf(sm[2], sm[3]));
    float inv = 1.0f / (m + EPSF);
    float4* od = (float4*)(out + (size_t)b * (HW_ * HW_));
    #pragma unroll
    for (int i = 0; i < 4; ++i) {
        float4 v = s[i];
        v.x *= inv; v.y *= inv; v.z *= inv; v.w *= inv;
        od[tid + i * 256] = v;
    }

    // ---- landscapes: merge PCW partial top-5 lists for r = tid ----
    float v0 = 0.f, v1 = 0.f, v2 = 0.f, v3 = 0.f, v4 = 0.f;
    const float* lpb = lp + (size_t)b * PCW * 5 * RES_;
    for (int pc = 0; pc < PCW; ++pc) {
        #pragma unroll
        for (int lvl = 0; lvl < 5; ++lvl) {
            float x = lpb[(pc * 5 + lvl) * RES_ + tid];
            INS5(v0, v1, v2, v3, v4, x);
        }
    }
    float* o = out + (size_t)B_ * HW_ * HW_ + (size_t)b * (5 * RES_);
    o[tid]            = v0;
    o[RES_ + tid]     = v1;
    o[2 * RES_ + tid] = v2;
    o[3 * RES_ + tid] = v3;
    o[4 * RES_ + tid] = v4;
}

extern "C" void kernel_launch(void* const* d_in, const int* in_sizes, int n_in,
                              void* d_out, int out_size, void* d_ws, size_t ws_size,
                              hipStream_t stream) {
    const float* pairs = (const float*)d_in[0];
    const float* sig   = (const float*)d_in[1];
    float* out = (float*)d_out;
    float* wsf = (float*)d_ws;

    // ws layout (floats): [0..127] min/max | part (B*KC*4096 = 1M) | lp (B*32*5*256 = 2.62M)
    float* part = wsf + 128;
    float* lp   = part + (size_t)B_ * KC_ * HW_ * HW_;

    k_minmax<<<B_, 256, 0, stream>>>(pairs, wsf);
    k_main<<<768, 256, 0, stream>>>(pairs, sig, wsf, part, lp);
    k_finish<<<B_, 256, 0, stream>>>(part, lp, out);
}